// Round 20
// baseline (342.078 us; speedup 1.0000x reference)
//
#include <hip/hip_runtime.h>
#include <cstdint>
#include <cstddef>

#define D_MODEL 1024
#define HEADS   16
#define DKH     64
#define D_FF    2048
#define SEQ     1024
#define BATCH   8
#define MROWS   (BATCH*SEQ)
#define LN_EPS  1e-6f

typedef __bf16 bh8 __attribute__((ext_vector_type(8)));
typedef float  f32x4 __attribute__((ext_vector_type(4)));
typedef unsigned short us8 __attribute__((ext_vector_type(8)));

// native bf16 convert (RNE): compiler emits v_cvt_pk_bf16_f32 for pairs.
__device__ __forceinline__ unsigned short f2bf(float f) {
  return __builtin_bit_cast(unsigned short, (__bf16)f);
}
__device__ __forceinline__ float bf2f(unsigned short h) {
  union { unsigned int u; float f; } c; c.u = ((unsigned int)h) << 16;
  return c.f;
}

__device__ __forceinline__ bh8 as_bh8(us8 v) { return __builtin_bit_cast(bh8, v); }

// async global->LDS, 16B per lane. Dest must be wave-uniform base + lane*16.
__device__ __forceinline__ void gl16(const unsigned short* g, unsigned short* l) {
  __builtin_amdgcn_global_load_lds(
      (const __attribute__((address_space(1))) unsigned int*)g,
      (__attribute__((address_space(3))) unsigned int*)l, 16, 0, 0);
}

// ---------------------------------------------------------------------------
// single cast launch. x = segs 0-7, Wq/Wk/Wv = 8-10, Wo = 11, W1 = 12-13,
// W2 = 14-15. 16 segs = 4,194,304 f4 -> grid 16384 x 256.
// ---------------------------------------------------------------------------
__global__ void castall_k(const float* __restrict__ x,
                          const float* __restrict__ wq, const float* __restrict__ wk,
                          const float* __restrict__ wv, const float* __restrict__ wo,
                          const float* __restrict__ w1, const float* __restrict__ w2,
                          unsigned short* __restrict__ xb,
                          unsigned short* __restrict__ oqkv, unsigned short* __restrict__ oo,
                          unsigned short* __restrict__ o1, unsigned short* __restrict__ o2) {
  int i = blockIdx.x * blockDim.x + threadIdx.x;   // f4 index, 4M total
  const int seg = i >> 18;                          // 262,144 f4 per seg
  const int loc = i & 262143;
  const float* src; unsigned short* dst; int il, ol;
  if (seg < 8)       { src = x; dst = xb; il = i; ol = i; }
  else if (seg < 11) { src = (seg == 8) ? wq : (seg == 9) ? wk : wv; dst = oqkv; il = loc; ol = (seg - 8) * 262144 + loc; }
  else if (seg == 11){ src = wo; dst = oo; il = loc; ol = loc; }
  else if (seg < 14) { src = w1; dst = o1; il = (seg - 12) * 262144 + loc; ol = il; }
  else               { src = w2; dst = o2; il = (seg - 14) * 262144 + loc; ol = il; }
  float4 v = ((const float4*)src)[il];
  ushort4 o;
  o.x = f2bf(v.x); o.y = f2bf(v.y); o.z = f2bf(v.z); o.w = f2bf(v.w);
  ((ushort4*)dst)[ol] = o;
}

// ---------------------------------------------------------------------------
// GEMM (validated r10): BK=64, double-buffered LDS, counted-vmcnt pipeline
// (distance 2; tile t+1's 8 DMAs stay in flight across barriers — T4).
// Bijective XCD chunk swizzle on block ids.
// EPI 2: f32 out0 = acc+bias+resid_f32  (Wo, FF2 — z1/z2 MUST be f32)
// EPI 3: bf16 out0 = relu(acc+bias)     (FF1)
// EPI 4: merged QKV: third 0 -> Q, 1 -> K, 2 -> Vt[(b*D+n)*S+s]
// ---------------------------------------------------------------------------
#define BM 128
#define BN 128
#define BK 64

template<int EPI>
__global__ __launch_bounds__(256)
void gemm_bt(const unsigned short* __restrict__ A, const unsigned short* __restrict__ Bw,
             const float* __restrict__ b0, const float* __restrict__ b1f,
             const float* __restrict__ b2f, const float* __restrict__ resid,
             void* __restrict__ out0, void* __restrict__ out1, void* __restrict__ out2,
             int M, int N, int K)
{
  __shared__ __align__(16) unsigned short As[2][BM * BK];   // 16 KB per buf
  __shared__ __align__(16) unsigned short Bs[2][BM * BK];   // 64 KB total

  const int tid  = threadIdx.x;
  const int lane = tid & 63;
  const int w    = tid >> 6;
  const int wr   = w >> 1;
  const int wc   = w & 1;
  const int l15  = lane & 15;
  const int l4   = lane >> 4;

  // bijective XCD chunk swizzle (nwg % 8 == 0 for all our grids)
  const int gx  = gridDim.x;
  const int nwg = gx * gridDim.y;
  int lin = blockIdx.y * gx + blockIdx.x;
  lin = (lin & 7) * (nwg >> 3) + (lin >> 3);
  const int brow = (lin / gx) * BM;
  const int bcol = (lin % gx) * BN;

  // staging: chunk c -> row c>>3, phys slot c&7, content slot (c&7)^(row&7)
  int rowj[4], offj[4];
  #pragma unroll
  for (int j = 0; j < 4; ++j) {
    const int c = tid + j * 256;
    rowj[j] = c >> 3;
    offj[j] = ((c & 7) ^ ((c >> 3) & 7)) * 8;
  }

  const unsigned short* Ag = A  + (size_t)brow * K;
  const unsigned short* Bg = Bw + (size_t)bcol * K;

  auto stage = [&](int bsel, int k0) {
    #pragma unroll
    for (int j = 0; j < 4; ++j)
      gl16(Ag + (size_t)rowj[j] * K + k0 + offj[j], &As[bsel][(tid + j * 256) * 8]);
    #pragma unroll
    for (int j = 0; j < 4; ++j)
      gl16(Bg + (size_t)rowj[j] * K + k0 + offj[j], &Bs[bsel][(tid + j * 256) * 8]);
  };

  const int NT = K / BK;
  stage(0, 0);
  stage(1, BK);

  f32x4 acc[4][4] = {};
  const int sw7 = l15 & 7;

  for (int t = 0; t < NT; ++t) {
    const int cur = t & 1;
    if (t + 1 < NT) { asm volatile("s_waitcnt vmcnt(8)" ::: "memory"); }
    else            { asm volatile("s_waitcnt vmcnt(0)" ::: "memory"); }
    __builtin_amdgcn_s_barrier();      // all waves: tile t landed

    us8 aF[2][4], bF[2][4];
    #pragma unroll
    for (int h = 0; h < 2; ++h) {
      const int slot = ((h * 4 + l4) ^ sw7) * 8;
      #pragma unroll
      for (int mi = 0; mi < 4; ++mi)
        aF[h][mi] = *(const us8*)(&As[cur][(wr * 64 + mi * 16 + l15) * BK + slot]);
      #pragma unroll
      for (int ni = 0; ni < 4; ++ni)
        bF[h][ni] = *(const us8*)(&Bs[cur][(wc * 64 + ni * 16 + l15) * BK + slot]);
    }
    asm volatile("s_waitcnt lgkmcnt(0)" ::: "memory");   // this wave's frags in regs
    __builtin_amdgcn_s_barrier();      // all waves done reading buf cur

    if (t + 2 < NT) stage(cur, (t + 2) * BK);  // overwrite cur; lands by iter t+2

    #pragma unroll
    for (int h = 0; h < 2; ++h)
      #pragma unroll
      for (int mi = 0; mi < 4; ++mi)
        #pragma unroll
        for (int ni = 0; ni < 4; ++ni)
          acc[mi][ni] = __builtin_amdgcn_mfma_f32_16x16x32_bf16(
              as_bh8(aF[h][mi]), as_bh8(bF[h][ni]), acc[mi][ni], 0, 0, 0);
  }

  // epilogue: D layout col = lane&15, row = (lane>>4)*4 + v
  const int tt = bcol >> 10;         // QKV third (EPI 4)
  #pragma unroll
  for (int mi = 0; mi < 4; ++mi) {
    #pragma unroll
    for (int ni = 0; ni < 4; ++ni) {
      const int gcol = bcol + wc * 64 + ni * 16 + l15;
      if (EPI == 4) {
        const int ccol = gcol & 1023;
        const float bv = ((tt == 0) ? b0 : (tt == 1) ? b1f : b2f)[ccol];
        const int grow0 = brow + wr * 64 + mi * 16 + l4 * 4;
        if (tt == 2) {               // V: transposed per head  Vt[(b*D+n)*S+s]
          const int bb = grow0 >> 10;
          const int s0 = grow0 & 1023;
          ushort4 pk;
          pk.x = f2bf(acc[mi][ni][0] + bv);
          pk.y = f2bf(acc[mi][ni][1] + bv);
          pk.z = f2bf(acc[mi][ni][2] + bv);
          pk.w = f2bf(acc[mi][ni][3] + bv);
          *(ushort4*)((unsigned short*)out2 + ((size_t)bb * D_MODEL + ccol) * SEQ + s0) = pk;
        } else {
          unsigned short* ob = (unsigned short*)(tt == 0 ? out0 : out1);
          #pragma unroll
          for (int v = 0; v < 4; ++v)
            ob[(size_t)(grow0 + v) * D_MODEL + ccol] = f2bf(acc[mi][ni][v] + bv);
        }
      } else {
        const float bv = b0[gcol];
        #pragma unroll
        for (int v = 0; v < 4; ++v) {
          const int grow = brow + wr * 64 + mi * 16 + l4 * 4 + v;
          float val = acc[mi][ni][v] + bv;
          if (EPI == 3) {
            val = fmaxf(val, 0.0f);
            ((unsigned short*)out0)[(size_t)grow * N + gcol] = f2bf(val);
          } else if (EPI == 2) {
            val += resid[(size_t)grow * N + gcol];
            ((float*)out0)[(size_t)grow * N + gcol] = val;
          }
        }
      }
    }
  }
}

// ---------------------------------------------------------------------------
// Flash attention — V read DIRECTLY from L2-resident global (no LDS staging;
// guide common-mistake #7 / m169: staging L2-fit data is pure overhead).
// K keeps distance-1 LDS double-buffer with a single __syncthreads per tile.
// LDS: Ks 16KB + Pl 9KB = 25.6KB -> 6 blocks/CU (was 44KB -> 3; occupancy
// cap 27% -> ~75%). V fragment addresses are identical values to the old
// swizzled stage/read pair (it was an involution), so numerics unchanged.
// No-max softmax with mask/scale/log2e FOLDED INTO Q; native v_exp_f32;
// native cvt for P->bf16. Bijective XCD swizzle (2048 blocks, 256/XCD).
// ---------------------------------------------------------------------------
__global__ __launch_bounds__(256)
void attn_k(const unsigned short* __restrict__ Q, const unsigned short* __restrict__ Kb,
            const unsigned short* __restrict__ Vt, const int* __restrict__ mask,
            unsigned short* __restrict__ O)
{
  __shared__ __align__(16) unsigned short Ks[2][64][64];   // 16 KB
  __shared__ __align__(16) unsigned short Pl[4][16][72];   // 9 KB (pad 8)

  const int bid = (blockIdx.x & 7) * 256 + (blockIdx.x >> 3);   // 2048 blocks
  const int qc = bid & 15;
  const int h  = (bid >> 4) & 15;
  const int b  = bid >> 8;
  const int q0 = qc * 64;

  const int tid  = threadIdx.x;
  const int lane = tid & 63;
  const int w    = tid >> 6;
  const int l15  = lane & 15;
  const int l4   = lane >> 4;

  const int c0 = tid, c1 = tid + 256;
  const int kr0 = c0 >> 3, ke0 = ((c0 & 7) ^ (kr0 & 7)) * 8;
  const int kr1 = c1 >> 3, ke1 = ((c1 & 7) ^ (kr1 & 7)) * 8;

  const unsigned short* Kbase = Kb + ((size_t)b * SEQ) * D_MODEL + h * DKH;
  const unsigned short* Vbase = Vt + ((size_t)b * D_MODEL + h * DKH) * SEQ;

  // Q fragments, prescaled by 0.125*log2(e)*mask[row] (A-frag row = l15)
  const unsigned short* qp = Q + ((size_t)(b * SEQ + q0 + w * 16 + l15)) * D_MODEL + h * DKH + l4 * 8;
  const float qs = mask[b * SEQ + q0 + w * 16 + l15] ? 0.18033688011112042f : 0.0f;
  us8 q0r = *(const us8*)qp;
  us8 q1r = *(const us8*)(qp + 32);
  us8 q0s, q1s;
  #pragma unroll
  for (int j = 0; j < 8; ++j) {
    q0s[j] = f2bf(bf2f(q0r[j]) * qs);
    q1s[j] = f2bf(bf2f(q1r[j]) * qs);
  }
  const bh8 aQ0 = as_bh8(q0s);
  const bh8 aQ1 = as_bh8(q1s);

  float l[4] = {0.f, 0.f, 0.f, 0.f};
  f32x4 oacc[4] = {};

  auto stageK = [&](int bsel, int kv) {
    gl16(Kbase + (size_t)(kv + kr0) * D_MODEL + ke0, &Ks[bsel][0][0] + c0 * 8);
    gl16(Kbase + (size_t)(kv + kr1) * D_MODEL + ke1, &Ks[bsel][0][0] + c1 * 8);
  };

  stageK(0, 0);                       // distance-1 prologue (K only)

  const int swz = l15 & 7;
  // per-lane V base: row = ds*16 + l15 fixed component l15
  const unsigned short* vlane = Vbase + (size_t)l15 * SEQ + l4 * 8;

  for (int t = 0; t < 16; ++t) {
    const int cur = t & 1;
    __syncthreads();                  // stage(t) K landed; prior reads of cur^1 done

    // K fragments from LDS
    us8 kF[4][2];
    #pragma unroll
    for (int kt = 0; kt < 4; ++kt) {
      const int row = kt * 16 + l15;
      kF[kt][0] = *(const us8*)(&Ks[cur][row][(l4 ^ swz) * 8]);
      kF[kt][1] = *(const us8*)(&Ks[cur][row][((4 + l4) ^ swz) * 8]);
    }

    // V fragments DIRECT from global (L2 hit); latency hides under QK+exp+P
    us8 vF[2][4];
    const unsigned short* vp = vlane + t * 64;
    #pragma unroll
    for (int ks = 0; ks < 2; ++ks)
      #pragma unroll
      for (int ds = 0; ds < 4; ++ds)
        vF[ks][ds] = *(const us8*)(vp + (size_t)(ds * 16) * SEQ + ks * 32);

    if (t + 1 < 16) stageK(cur ^ 1, (t + 1) * 64);  // other buffer: no WAR

    // QK^T: S (16q x 64k), already scaled+masked via Q (log2 domain)
    f32x4 s[4];
    #pragma unroll
    for (int kt = 0; kt < 4; ++kt) {
      f32x4 t0 = {0.f, 0.f, 0.f, 0.f};
      t0 = __builtin_amdgcn_mfma_f32_16x16x32_bf16(aQ0, as_bh8(kF[kt][0]), t0, 0, 0, 0);
      t0 = __builtin_amdgcn_mfma_f32_16x16x32_bf16(aQ1, as_bh8(kF[kt][1]), t0, 0, 0, 0);
      s[kt] = t0;
    }

    // softmax numerator: one native v_exp_f32 per score
    #pragma unroll
    for (int v = 0; v < 4; ++v) {
      float ls = 0.f;
      #pragma unroll
      for (int kt = 0; kt < 4; ++kt) {
        float e = __builtin_amdgcn_exp2f(s[kt][v]);
        s[kt][v] = e;
        ls += e;
      }
      l[v] += ls;
    }

    // P -> per-wave LDS as bf16 (native cvt; same-wave write/read)
    #pragma unroll
    for (int kt = 0; kt < 4; ++kt)
      #pragma unroll
      for (int v = 0; v < 4; ++v)
        Pl[w][l4 * 4 + v][kt * 16 + l15] = f2bf(s[kt][v]);

    #pragma unroll
    for (int ks = 0; ks < 2; ++ks) {
      bh8 aP = as_bh8(*(const us8*)(&Pl[w][l15][ks * 32 + l4 * 8]));
      #pragma unroll
      for (int ds = 0; ds < 4; ++ds)
        oacc[ds] = __builtin_amdgcn_mfma_f32_16x16x32_bf16(aP, as_bh8(vF[ks][ds]), oacc[ds], 0, 0, 0);
    }
  }

  // epilogue: reduce l across the 16 lanes of each row group, write O
  #pragma unroll
  for (int v = 0; v < 4; ++v) {
    float lv = l[v];
    #pragma unroll
    for (int d = 1; d < 16; d <<= 1) lv += __shfl_xor(lv, d, 64);
    const float inv = 1.0f / lv;
    const int q = q0 + w * 16 + l4 * 4 + v;
    #pragma unroll
    for (int ds = 0; ds < 4; ++ds)
      O[((size_t)(b * SEQ + q)) * D_MODEL + h * DKH + ds * 16 + l15] =
          f2bf(oacc[ds][v] * inv);
  }
}

// ---------------------------------------------------------------------------
// "LayerNorm": y = (z - (z-mean)/(std+eps))*alpha + beta, std ddof=1.
// f32 in; f32 out (+optional bf16 copy).
// ---------------------------------------------------------------------------
template<bool WBF>
__global__ __launch_bounds__(256)
void ln_k(const float* __restrict__ z, const float* __restrict__ alpha,
          const float* __restrict__ beta, float* __restrict__ yf,
          unsigned short* __restrict__ yb)
{
  const int row = blockIdx.x;
  const int tid = threadIdx.x;
  const float4 v = ((const float4*)(z + (size_t)row * D_MODEL))[tid];
  float s  = v.x + v.y + v.z + v.w;
  float ss = v.x * v.x + v.y * v.y + v.z * v.z + v.w * v.w;
  #pragma unroll
  for (int d = 1; d < 64; d <<= 1) {
    s  += __shfl_xor(s, d, 64);
    ss += __shfl_xor(ss, d, 64);
  }
  __shared__ float red[8];
  const int w = tid >> 6;
  if ((tid & 63) == 0) { red[w * 2] = s; red[w * 2 + 1] = ss; }
  __syncthreads();
  const float S  = red[0] + red[2] + red[4] + red[6];
  const float SS = red[1] + red[3] + red[5] + red[7];
  const float mean = S * (1.0f / 1024.0f);
  float var = (SS - 1024.0f * mean * mean) * (1.0f / 1023.0f);
  var = fmaxf(var, 0.0f);
  const float invd = 1.0f / (sqrtf(var) + LN_EPS);

  const float4 a  = ((const float4*)alpha)[tid];
  const float4 be = ((const float4*)beta)[tid];
  float4 y;
  y.x = (v.x - (v.x - mean) * invd) * a.x + be.x;
  y.y = (v.y - (v.y - mean) * invd) * a.y + be.y;
  y.z = (v.z - (v.z - mean) * invd) * a.z + be.z;
  y.w = (v.w - (v.w - mean) * invd) * a.w + be.w;
  ((float4*)(yf + (size_t)row * D_MODEL))[tid] = y;
  if (WBF) {
    ushort4 pk;
    pk.x = f2bf(y.x); pk.y = f2bf(y.y); pk.z = f2bf(y.z); pk.w = f2bf(y.w);
    ((ushort4*)(yb + (size_t)row * D_MODEL))[tid] = pk;
  }
}

// ---------------------------------------------------------------------------
extern "C" void kernel_launch(void* const* d_in, const int* in_sizes, int n_in,
                              void* d_out, int out_size, void* d_ws, size_t ws_size,
                              hipStream_t stream) {
  const float* x    = (const float*)d_in[0];
  const int*   mask = (const int*)d_in[1];
  const float* Wq = (const float*)d_in[2];  const float* bq = (const float*)d_in[3];
  const float* Wk = (const float*)d_in[4];  const float* bk = (const float*)d_in[5];
  const float* Wv = (const float*)d_in[6];  const float* bv = (const float*)d_in[7];
  const float* Wo = (const float*)d_in[8];  const float* bo = (const float*)d_in[9];
  const float* W1 = (const float*)d_in[10]; const float* b1 = (const float*)d_in[11];
  const float* W2 = (const float*)d_in[12]; const float* b2 = (const float*)d_in[13];
  const float* alpha1 = (const float*)d_in[14]; const float* beta1 = (const float*)d_in[15];
  const float* alpha2 = (const float*)d_in[16]; const float* beta2 = (const float*)d_in[17];
  (void)in_sizes; (void)n_in; (void)out_size; (void)ws_size;

  char* ws = (char*)d_ws;
  const size_t MB = (size_t)1 << 20;
  unsigned short* xb    = (unsigned short*)(ws + 0 * MB);    // 16 MB
  unsigned short* Wqkvb = (unsigned short*)(ws + 16 * MB);   // 6 MB (3072x1024)
  unsigned short* Wob   = (unsigned short*)(ws + 22 * MB);   // 2 MB
  unsigned short* W1b   = (unsigned short*)(ws + 24 * MB);   // 4 MB
  unsigned short* W2b   = (unsigned short*)(ws + 28 * MB);   // 4 MB
  unsigned short* Qb    = (unsigned short*)(ws + 32 * MB);   // 16 MB
  unsigned short* Kb2   = (unsigned short*)(ws + 48 * MB);   // 16 MB
  unsigned short* Vt    = (unsigned short*)(ws + 64 * MB);   // 16 MB
  unsigned short* Ob    = (unsigned short*)(ws + 80 * MB);   // 16 MB
  float*          zf    = (float*)(ws + 96 * MB);            // 32 MB (z1, then z2)
  float*          x1f   = (float*)(ws + 128 * MB);           // 32 MB
  unsigned short* x1b   = (unsigned short*)(ws + 160 * MB);  // 16 MB
  unsigned short* hb    = Qb;   // reuse Qb+Kb2 (32 MB) after attention

  // single cast launch: x + all weights (4,194,304 float4 -> 16384 blocks)
  castall_k<<<16384, 256, 0, stream>>>(x, Wq, Wk, Wv, Wo, W1, W2,
                                       xb, Wqkvb, Wob, W1b, W2b);

  // merged QKV projection (N = 3072)
  gemm_bt<4><<<dim3(24, 64), 256, 0, stream>>>(xb, Wqkvb, bq, bk, bv, nullptr,
                                               Qb, Kb2, Vt, MROWS, 3072, D_MODEL);

  attn_k<<<BATCH * HEADS * (SEQ / 64), 256, 0, stream>>>(Qb, Kb2, Vt, mask, Ob);

  // Wo projection + f32 residual x -> z1 (f32)
  gemm_bt<2><<<dim3(8, 64), 256, 0, stream>>>(Ob, Wob, bo, nullptr, nullptr, x,
                                              zf, nullptr, nullptr, MROWS, D_MODEL, D_MODEL);
  ln_k<true><<<MROWS, 256, 0, stream>>>(zf, alpha1, beta1, x1f, x1b);

  gemm_bt<3><<<dim3(16, 64), 256, 0, stream>>>(x1b, W1b, b1, nullptr, nullptr, nullptr,
                                               hb, nullptr, nullptr, MROWS, D_FF, D_MODEL);
  gemm_bt<2><<<dim3(8, 64), 256, 0, stream>>>(hb, W2b, b2, nullptr, nullptr, x1f,
                                              zf, nullptr, nullptr, MROWS, D_MODEL, D_FF);

  ln_k<false><<<MROWS, 256, 0, stream>>>(zf, alpha2, beta2, (float*)d_out, nullptr);
}

// Round 21
// 275.603 us; speedup vs baseline: 1.2412x; 1.2412x over previous
//
#include <hip/hip_runtime.h>
#include <cstdint>
#include <cstddef>

#define D_MODEL 1024
#define HEADS   16
#define DKH     64
#define D_FF    2048
#define SEQ     1024
#define BATCH   8
#define MROWS   (BATCH*SEQ)
#define LN_EPS  1e-6f

typedef __bf16 bh8 __attribute__((ext_vector_type(8)));
typedef float  f32x4 __attribute__((ext_vector_type(4)));
typedef unsigned short us8 __attribute__((ext_vector_type(8)));

// native bf16 convert (RNE): compiler emits v_cvt_pk_bf16_f32 for pairs.
__device__ __forceinline__ unsigned short f2bf(float f) {
  return __builtin_bit_cast(unsigned short, (__bf16)f);
}
__device__ __forceinline__ float bf2f(unsigned short h) {
  union { unsigned int u; float f; } c; c.u = ((unsigned int)h) << 16;
  return c.f;
}

__device__ __forceinline__ bh8 as_bh8(us8 v) { return __builtin_bit_cast(bh8, v); }

// async global->LDS, 16B per lane. Dest must be wave-uniform base + lane*16.
__device__ __forceinline__ void gl16(const unsigned short* g, unsigned short* l) {
  __builtin_amdgcn_global_load_lds(
      (const __attribute__((address_space(1))) unsigned int*)g,
      (__attribute__((address_space(3))) unsigned int*)l, 16, 0, 0);
}

// ---------------------------------------------------------------------------
// single cast launch. x = segs 0-7, Wq/Wk/Wv = 8-10, Wo = 11, W1 = 12-13,
// W2 = 14-15. 16 segs = 4,194,304 f4 -> grid 16384 x 256.
// ---------------------------------------------------------------------------
__global__ void castall_k(const float* __restrict__ x,
                          const float* __restrict__ wq, const float* __restrict__ wk,
                          const float* __restrict__ wv, const float* __restrict__ wo,
                          const float* __restrict__ w1, const float* __restrict__ w2,
                          unsigned short* __restrict__ xb,
                          unsigned short* __restrict__ oqkv, unsigned short* __restrict__ oo,
                          unsigned short* __restrict__ o1, unsigned short* __restrict__ o2) {
  int i = blockIdx.x * blockDim.x + threadIdx.x;   // f4 index, 4M total
  const int seg = i >> 18;                          // 262,144 f4 per seg
  const int loc = i & 262143;
  const float* src; unsigned short* dst; int il, ol;
  if (seg < 8)       { src = x; dst = xb; il = i; ol = i; }
  else if (seg < 11) { src = (seg == 8) ? wq : (seg == 9) ? wk : wv; dst = oqkv; il = loc; ol = (seg - 8) * 262144 + loc; }
  else if (seg == 11){ src = wo; dst = oo; il = loc; ol = loc; }
  else if (seg < 14) { src = w1; dst = o1; il = (seg - 12) * 262144 + loc; ol = il; }
  else               { src = w2; dst = o2; il = (seg - 14) * 262144 + loc; ol = il; }
  float4 v = ((const float4*)src)[il];
  ushort4 o;
  o.x = f2bf(v.x); o.y = f2bf(v.y); o.z = f2bf(v.z); o.w = f2bf(v.w);
  ((ushort4*)dst)[ol] = o;
}

// ---------------------------------------------------------------------------
// GEMM (validated r10): BK=64, double-buffered LDS, counted-vmcnt pipeline
// (distance 2; tile t+1's 8 DMAs stay in flight across barriers — T4).
// Bijective XCD chunk swizzle on block ids.
// EPI 2: f32 out0 = acc+bias+resid_f32  (Wo, FF2 — z1/z2 MUST be f32)
// EPI 3: bf16 out0 = relu(acc+bias)     (FF1)
// EPI 4: merged QKV: third 0 -> Q, 1 -> K, 2 -> Vt[(b*D+n)*S+s]
// ---------------------------------------------------------------------------
#define BM 128
#define BN 128
#define BK 64

template<int EPI>
__global__ __launch_bounds__(256)
void gemm_bt(const unsigned short* __restrict__ A, const unsigned short* __restrict__ Bw,
             const float* __restrict__ b0, const float* __restrict__ b1f,
             const float* __restrict__ b2f, const float* __restrict__ resid,
             void* __restrict__ out0, void* __restrict__ out1, void* __restrict__ out2,
             int M, int N, int K)
{
  __shared__ __align__(16) unsigned short As[2][BM * BK];   // 16 KB per buf
  __shared__ __align__(16) unsigned short Bs[2][BM * BK];   // 64 KB total

  const int tid  = threadIdx.x;
  const int lane = tid & 63;
  const int w    = tid >> 6;
  const int wr   = w >> 1;
  const int wc   = w & 1;
  const int l15  = lane & 15;
  const int l4   = lane >> 4;

  // bijective XCD chunk swizzle (nwg % 8 == 0 for all our grids)
  const int gx  = gridDim.x;
  const int nwg = gx * gridDim.y;
  int lin = blockIdx.y * gx + blockIdx.x;
  lin = (lin & 7) * (nwg >> 3) + (lin >> 3);
  const int brow = (lin / gx) * BM;
  const int bcol = (lin % gx) * BN;

  // staging: chunk c -> row c>>3, phys slot c&7, content slot (c&7)^(row&7)
  int rowj[4], offj[4];
  #pragma unroll
  for (int j = 0; j < 4; ++j) {
    const int c = tid + j * 256;
    rowj[j] = c >> 3;
    offj[j] = ((c & 7) ^ ((c >> 3) & 7)) * 8;
  }

  const unsigned short* Ag = A  + (size_t)brow * K;
  const unsigned short* Bg = Bw + (size_t)bcol * K;

  auto stage = [&](int bsel, int k0) {
    #pragma unroll
    for (int j = 0; j < 4; ++j)
      gl16(Ag + (size_t)rowj[j] * K + k0 + offj[j], &As[bsel][(tid + j * 256) * 8]);
    #pragma unroll
    for (int j = 0; j < 4; ++j)
      gl16(Bg + (size_t)rowj[j] * K + k0 + offj[j], &Bs[bsel][(tid + j * 256) * 8]);
  };

  const int NT = K / BK;
  stage(0, 0);
  stage(1, BK);

  f32x4 acc[4][4] = {};
  const int sw7 = l15 & 7;

  for (int t = 0; t < NT; ++t) {
    const int cur = t & 1;
    if (t + 1 < NT) { asm volatile("s_waitcnt vmcnt(8)" ::: "memory"); }
    else            { asm volatile("s_waitcnt vmcnt(0)" ::: "memory"); }
    __builtin_amdgcn_s_barrier();      // all waves: tile t landed

    us8 aF[2][4], bF[2][4];
    #pragma unroll
    for (int h = 0; h < 2; ++h) {
      const int slot = ((h * 4 + l4) ^ sw7) * 8;
      #pragma unroll
      for (int mi = 0; mi < 4; ++mi)
        aF[h][mi] = *(const us8*)(&As[cur][(wr * 64 + mi * 16 + l15) * BK + slot]);
      #pragma unroll
      for (int ni = 0; ni < 4; ++ni)
        bF[h][ni] = *(const us8*)(&Bs[cur][(wc * 64 + ni * 16 + l15) * BK + slot]);
    }
    asm volatile("s_waitcnt lgkmcnt(0)" ::: "memory");   // this wave's frags in regs
    __builtin_amdgcn_s_barrier();      // all waves done reading buf cur

    if (t + 2 < NT) stage(cur, (t + 2) * BK);  // overwrite cur; lands by iter t+2

    #pragma unroll
    for (int h = 0; h < 2; ++h)
      #pragma unroll
      for (int mi = 0; mi < 4; ++mi)
        #pragma unroll
        for (int ni = 0; ni < 4; ++ni)
          acc[mi][ni] = __builtin_amdgcn_mfma_f32_16x16x32_bf16(
              as_bh8(aF[h][mi]), as_bh8(bF[h][ni]), acc[mi][ni], 0, 0, 0);
  }

  // epilogue: D layout col = lane&15, row = (lane>>4)*4 + v
  const int tt = bcol >> 10;         // QKV third (EPI 4)
  #pragma unroll
  for (int mi = 0; mi < 4; ++mi) {
    #pragma unroll
    for (int ni = 0; ni < 4; ++ni) {
      const int gcol = bcol + wc * 64 + ni * 16 + l15;
      if (EPI == 4) {
        const int ccol = gcol & 1023;
        const float bv = ((tt == 0) ? b0 : (tt == 1) ? b1f : b2f)[ccol];
        const int grow0 = brow + wr * 64 + mi * 16 + l4 * 4;
        if (tt == 2) {               // V: transposed per head  Vt[(b*D+n)*S+s]
          const int bb = grow0 >> 10;
          const int s0 = grow0 & 1023;
          ushort4 pk;
          pk.x = f2bf(acc[mi][ni][0] + bv);
          pk.y = f2bf(acc[mi][ni][1] + bv);
          pk.z = f2bf(acc[mi][ni][2] + bv);
          pk.w = f2bf(acc[mi][ni][3] + bv);
          *(ushort4*)((unsigned short*)out2 + ((size_t)bb * D_MODEL + ccol) * SEQ + s0) = pk;
        } else {
          unsigned short* ob = (unsigned short*)(tt == 0 ? out0 : out1);
          #pragma unroll
          for (int v = 0; v < 4; ++v)
            ob[(size_t)(grow0 + v) * D_MODEL + ccol] = f2bf(acc[mi][ni][v] + bv);
        }
      } else {
        const float bv = b0[gcol];
        #pragma unroll
        for (int v = 0; v < 4; ++v) {
          const int grow = brow + wr * 64 + mi * 16 + l4 * 4 + v;
          float val = acc[mi][ni][v] + bv;
          if (EPI == 3) {
            val = fmaxf(val, 0.0f);
            ((unsigned short*)out0)[(size_t)grow * N + gcol] = f2bf(val);
          } else if (EPI == 2) {
            val += resid[(size_t)grow * N + gcol];
            ((float*)out0)[(size_t)grow * N + gcol] = val;
          }
        }
      }
    }
  }
}

// ---------------------------------------------------------------------------
// Flash attention (r19, best validated): distance-1 K/V double-buffer with a
// single __syncthreads per tile (stage targets the buffer not being read).
// V staged via gl16 (COALESCED; direct per-lane V reads stride 2KB and
// exploded the L2 request rate — r20: 66.7 -> 137us).
// No-max softmax with mask/scale/log2e FOLDED INTO Q; native v_exp_f32;
// native cvt for P->bf16. Bijective XCD swizzle (2048 blocks, 256/XCD).
// ---------------------------------------------------------------------------
__global__ __launch_bounds__(256)
void attn_k(const unsigned short* __restrict__ Q, const unsigned short* __restrict__ Kb,
            const unsigned short* __restrict__ Vt, const int* __restrict__ mask,
            unsigned short* __restrict__ O)
{
  __shared__ __align__(16) unsigned short Ks[2][64][64];
  __shared__ __align__(16) unsigned short Vs[2][64][64];
  __shared__ __align__(16) unsigned short Pl[4][16][88];

  const int bid = (blockIdx.x & 7) * 256 + (blockIdx.x >> 3);   // 2048 blocks
  const int qc = bid & 15;
  const int h  = (bid >> 4) & 15;
  const int b  = bid >> 8;
  const int q0 = qc * 64;

  const int tid  = threadIdx.x;
  const int lane = tid & 63;
  const int w    = tid >> 6;
  const int l15  = lane & 15;
  const int l4   = lane >> 4;

  const int c0 = tid, c1 = tid + 256;
  const int kr0 = c0 >> 3, ke0 = ((c0 & 7) ^ (kr0 & 7)) * 8;
  const int kr1 = c1 >> 3, ke1 = ((c1 & 7) ^ (kr1 & 7)) * 8;

  const unsigned short* Kbase = Kb + ((size_t)b * SEQ) * D_MODEL + h * DKH;
  const unsigned short* Vbase = Vt + ((size_t)b * D_MODEL + h * DKH) * SEQ;

  // Q fragments, prescaled by 0.125*log2(e)*mask[row] (A-frag row = l15)
  const unsigned short* qp = Q + ((size_t)(b * SEQ + q0 + w * 16 + l15)) * D_MODEL + h * DKH + l4 * 8;
  const float qs = mask[b * SEQ + q0 + w * 16 + l15] ? 0.18033688011112042f : 0.0f;
  us8 q0r = *(const us8*)qp;
  us8 q1r = *(const us8*)(qp + 32);
  us8 q0s, q1s;
  #pragma unroll
  for (int j = 0; j < 8; ++j) {
    q0s[j] = f2bf(bf2f(q0r[j]) * qs);
    q1s[j] = f2bf(bf2f(q1r[j]) * qs);
  }
  const bh8 aQ0 = as_bh8(q0s);
  const bh8 aQ1 = as_bh8(q1s);

  float l[4] = {0.f, 0.f, 0.f, 0.f};
  f32x4 oacc[4] = {};

  auto stageKV = [&](int bsel, int kv) {
    gl16(Kbase + (size_t)(kv + kr0) * D_MODEL + ke0, &Ks[bsel][0][0] + c0 * 8);
    gl16(Kbase + (size_t)(kv + kr1) * D_MODEL + ke1, &Ks[bsel][0][0] + c1 * 8);
    gl16(Vbase + (size_t)kr0 * SEQ + kv + ke0,       &Vs[bsel][0][0] + c0 * 8);
    gl16(Vbase + (size_t)kr1 * SEQ + kv + ke1,       &Vs[bsel][0][0] + c1 * 8);
  };

  stageKV(0, 0);                      // distance-1 prologue

  const int swz = l15 & 7;

  for (int t = 0; t < 16; ++t) {
    const int cur = t & 1;
    __syncthreads();                  // stage(t) landed; prior reads of cur^1 done

    // pull ALL K and V fragments of buf[cur] into registers
    us8 kF[4][2], vF[2][4];
    #pragma unroll
    for (int kt = 0; kt < 4; ++kt) {
      const int row = kt * 16 + l15;
      kF[kt][0] = *(const us8*)(&Ks[cur][row][(l4 ^ swz) * 8]);
      kF[kt][1] = *(const us8*)(&Ks[cur][row][((4 + l4) ^ swz) * 8]);
    }
    #pragma unroll
    for (int ks = 0; ks < 2; ++ks)
      #pragma unroll
      for (int ds = 0; ds < 4; ++ds) {
        const int row = ds * 16 + l15;
        vF[ks][ds] = *(const us8*)(&Vs[cur][row][((ks * 4 + l4) ^ swz) * 8]);
      }

    if (t + 1 < 16) stageKV(cur ^ 1, (t + 1) * 64);  // other buffer: no WAR

    // QK^T: S (16q x 64k), already scaled+masked via Q (log2 domain)
    f32x4 s[4];
    #pragma unroll
    for (int kt = 0; kt < 4; ++kt) {
      f32x4 t0 = {0.f, 0.f, 0.f, 0.f};
      t0 = __builtin_amdgcn_mfma_f32_16x16x32_bf16(aQ0, as_bh8(kF[kt][0]), t0, 0, 0, 0);
      t0 = __builtin_amdgcn_mfma_f32_16x16x32_bf16(aQ1, as_bh8(kF[kt][1]), t0, 0, 0, 0);
      s[kt] = t0;
    }

    // softmax numerator: one native v_exp_f32 per score
    #pragma unroll
    for (int v = 0; v < 4; ++v) {
      float ls = 0.f;
      #pragma unroll
      for (int kt = 0; kt < 4; ++kt) {
        float e = __builtin_amdgcn_exp2f(s[kt][v]);
        s[kt][v] = e;
        ls += e;
      }
      l[v] += ls;
    }

    // P -> per-wave LDS as bf16 (native cvt; same-wave write/read)
    #pragma unroll
    for (int kt = 0; kt < 4; ++kt)
      #pragma unroll
      for (int v = 0; v < 4; ++v)
        Pl[w][l4 * 4 + v][kt * 16 + l15] = f2bf(s[kt][v]);

    #pragma unroll
    for (int ks = 0; ks < 2; ++ks) {
      bh8 aP = as_bh8(*(const us8*)(&Pl[w][l15][ks * 32 + l4 * 8]));
      #pragma unroll
      for (int ds = 0; ds < 4; ++ds)
        oacc[ds] = __builtin_amdgcn_mfma_f32_16x16x32_bf16(aP, as_bh8(vF[ks][ds]), oacc[ds], 0, 0, 0);
    }
  }

  // epilogue: reduce l across the 16 lanes of each row group, write O
  #pragma unroll
  for (int v = 0; v < 4; ++v) {
    float lv = l[v];
    #pragma unroll
    for (int d = 1; d < 16; d <<= 1) lv += __shfl_xor(lv, d, 64);
    const float inv = 1.0f / lv;
    const int q = q0 + w * 16 + l4 * 4 + v;
    #pragma unroll
    for (int ds = 0; ds < 4; ++ds)
      O[((size_t)(b * SEQ + q)) * D_MODEL + h * DKH + ds * 16 + l15] =
          f2bf(oacc[ds][v] * inv);
  }
}

// ---------------------------------------------------------------------------
// "LayerNorm": y = (z - (z-mean)/(std+eps))*alpha + beta, std ddof=1.
// f32 in; f32 out (+optional bf16 copy).
// ---------------------------------------------------------------------------
template<bool WBF>
__global__ __launch_bounds__(256)
void ln_k(const float* __restrict__ z, const float* __restrict__ alpha,
          const float* __restrict__ beta, float* __restrict__ yf,
          unsigned short* __restrict__ yb)
{
  const int row = blockIdx.x;
  const int tid = threadIdx.x;
  const float4 v = ((const float4*)(z + (size_t)row * D_MODEL))[tid];
  float s  = v.x + v.y + v.z + v.w;
  float ss = v.x * v.x + v.y * v.y + v.z * v.z + v.w * v.w;
  #pragma unroll
  for (int d = 1; d < 64; d <<= 1) {
    s  += __shfl_xor(s, d, 64);
    ss += __shfl_xor(ss, d, 64);
  }
  __shared__ float red[8];
  const int w = tid >> 6;
  if ((tid & 63) == 0) { red[w * 2] = s; red[w * 2 + 1] = ss; }
  __syncthreads();
  const float S  = red[0] + red[2] + red[4] + red[6];
  const float SS = red[1] + red[3] + red[5] + red[7];
  const float mean = S * (1.0f / 1024.0f);
  float var = (SS - 1024.0f * mean * mean) * (1.0f / 1023.0f);
  var = fmaxf(var, 0.0f);
  const float invd = 1.0f / (sqrtf(var) + LN_EPS);

  const float4 a  = ((const float4*)alpha)[tid];
  const float4 be = ((const float4*)beta)[tid];
  float4 y;
  y.x = (v.x - (v.x - mean) * invd) * a.x + be.x;
  y.y = (v.y - (v.y - mean) * invd) * a.y + be.y;
  y.z = (v.z - (v.z - mean) * invd) * a.z + be.z;
  y.w = (v.w - (v.w - mean) * invd) * a.w + be.w;
  ((float4*)(yf + (size_t)row * D_MODEL))[tid] = y;
  if (WBF) {
    ushort4 pk;
    pk.x = f2bf(y.x); pk.y = f2bf(y.y); pk.z = f2bf(y.z); pk.w = f2bf(y.w);
    ((ushort4*)(yb + (size_t)row * D_MODEL))[tid] = pk;
  }
}

// ---------------------------------------------------------------------------
extern "C" void kernel_launch(void* const* d_in, const int* in_sizes, int n_in,
                              void* d_out, int out_size, void* d_ws, size_t ws_size,
                              hipStream_t stream) {
  const float* x    = (const float*)d_in[0];
  const int*   mask = (const int*)d_in[1];
  const float* Wq = (const float*)d_in[2];  const float* bq = (const float*)d_in[3];
  const float* Wk = (const float*)d_in[4];  const float* bk = (const float*)d_in[5];
  const float* Wv = (const float*)d_in[6];  const float* bv = (const float*)d_in[7];
  const float* Wo = (const float*)d_in[8];  const float* bo = (const float*)d_in[9];
  const float* W1 = (const float*)d_in[10]; const float* b1 = (const float*)d_in[11];
  const float* W2 = (const float*)d_in[12]; const float* b2 = (const float*)d_in[13];
  const float* alpha1 = (const float*)d_in[14]; const float* beta1 = (const float*)d_in[15];
  const float* alpha2 = (const float*)d_in[16]; const float* beta2 = (const float*)d_in[17];
  (void)in_sizes; (void)n_in; (void)out_size; (void)ws_size;

  char* ws = (char*)d_ws;
  const size_t MB = (size_t)1 << 20;
  unsigned short* xb    = (unsigned short*)(ws + 0 * MB);    // 16 MB
  unsigned short* Wqkvb = (unsigned short*)(ws + 16 * MB);   // 6 MB (3072x1024)
  unsigned short* Wob   = (unsigned short*)(ws + 22 * MB);   // 2 MB
  unsigned short* W1b   = (unsigned short*)(ws + 24 * MB);   // 4 MB
  unsigned short* W2b   = (unsigned short*)(ws + 28 * MB);   // 4 MB
  unsigned short* Qb    = (unsigned short*)(ws + 32 * MB);   // 16 MB
  unsigned short* Kb2   = (unsigned short*)(ws + 48 * MB);   // 16 MB
  unsigned short* Vt    = (unsigned short*)(ws + 64 * MB);   // 16 MB
  unsigned short* Ob    = (unsigned short*)(ws + 80 * MB);   // 16 MB
  float*          zf    = (float*)(ws + 96 * MB);            // 32 MB (z1, then z2)
  float*          x1f   = (float*)(ws + 128 * MB);           // 32 MB
  unsigned short* x1b   = (unsigned short*)(ws + 160 * MB);  // 16 MB
  unsigned short* hb    = Qb;   // reuse Qb+Kb2 (32 MB) after attention

  // single cast launch: x + all weights (4,194,304 float4 -> 16384 blocks)
  castall_k<<<16384, 256, 0, stream>>>(x, Wq, Wk, Wv, Wo, W1, W2,
                                       xb, Wqkvb, Wob, W1b, W2b);

  // merged QKV projection (N = 3072)
  gemm_bt<4><<<dim3(24, 64), 256, 0, stream>>>(xb, Wqkvb, bq, bk, bv, nullptr,
                                               Qb, Kb2, Vt, MROWS, 3072, D_MODEL);

  attn_k<<<BATCH * HEADS * (SEQ / 64), 256, 0, stream>>>(Qb, Kb2, Vt, mask, Ob);

  // Wo projection + f32 residual x -> z1 (f32)
  gemm_bt<2><<<dim3(8, 64), 256, 0, stream>>>(Ob, Wob, bo, nullptr, nullptr, x,
                                              zf, nullptr, nullptr, MROWS, D_MODEL, D_MODEL);
  ln_k<true><<<MROWS, 256, 0, stream>>>(zf, alpha1, beta1, x1f, x1b);

  gemm_bt<3><<<dim3(16, 64), 256, 0, stream>>>(x1b, W1b, b1, nullptr, nullptr, nullptr,
                                               hb, nullptr, nullptr, MROWS, D_FF, D_MODEL);
  gemm_bt<2><<<dim3(8, 64), 256, 0, stream>>>(hb, W2b, b2, nullptr, nullptr, x1f,
                                              zf, nullptr, nullptr, MROWS, D_MODEL, D_FF);

  ln_k<false><<<MROWS, 256, 0, stream>>>(zf, alpha2, beta2, (float*)d_out, nullptr);
}